// Round 5
// baseline (198.829 us; speedup 1.0000x reference)
//
#include <hip/hip_runtime.h>
#include <hip/hip_bf16.h>

typedef __attribute__((ext_vector_type(4))) float f32x4;
typedef __attribute__((ext_vector_type(8))) short bf16x8;

__device__ __forceinline__ void gload_lds16(const void* g, void* l) {
  __builtin_amdgcn_global_load_lds(
      (const __attribute__((address_space(1))) void*)g,
      (__attribute__((address_space(3))) void*)l, 16, 0, 0);
}

__device__ __forceinline__ unsigned short f2bf(float f) {
  union { float f; unsigned u; } x; x.f = f;
  unsigned r = x.u + 0x7fffu + ((x.u >> 16) & 1u);
  return (unsigned short)(r >> 16);
}

__device__ __forceinline__ float bf2f(unsigned short s) {
  union { unsigned u; float f; } x; x.u = (unsigned)s << 16;
  return x.f;
}

template<int N> __device__ __forceinline__ void vm_wait();
template<> __device__ __forceinline__ void vm_wait<0>() { asm volatile("s_waitcnt vmcnt(0)" ::: "memory"); }
template<> __device__ __forceinline__ void vm_wait<4>() { asm volatile("s_waitcnt vmcnt(4)" ::: "memory"); }
template<> __device__ __forceinline__ void vm_wait<6>() { asm volatile("s_waitcnt vmcnt(6)" ::: "memory"); }

#define BARRIER() asm volatile("s_barrier" ::: "memory")
#define SCHED0()  __builtin_amdgcn_sched_barrier(0)

// ---------------------------------------------------------------------------
// 256xBN 8-phase double-buffered GEMM: C = f(alpha * A[M][K] @ Bt[N][K]^T)
// EPI: 0 = alpha only, 1 = alpha + bias[col], 2 = alpha + bias[row],
//      3 = exp(alpha*acc) + atomic per-row sum into rs,
//      5 = acc * rcp(rs[row]) + bias[col],
//      6 = atomicAdd f32 (split-K partial accumulation).
// 512 threads, BK=64, T1 XCD swizzle, T2 LDS swizzle, T4 counted vmcnt, T5.
// ds_read->MFMA waits are compiler fine-grained (no hard lgkmcnt(0) drain);
// sched_barrier(0) pins the MFMA cluster inside its phase (rule #18).
// ---------------------------------------------------------------------------
template<int BN, int EPI, bool OUT_F32>
__global__ __launch_bounds__(512, 2)
void gemm256(const unsigned short* __restrict__ A,
             const unsigned short* __restrict__ Bt,
             const float* __restrict__ bias,
             float* __restrict__ rs,
             void* __restrict__ Cout,
             int K, int lda, int ldb, int ldc, float alpha,
             long sA, long sB, long sC)
{
  constexpr int THREADS = 512;
  constexpr int WN = BN / 64;          // waves along N (4 or 2)
  constexpr int WM = 8 / WN;           // waves along M (2 or 4)
  constexpr int WTM = 256 / WM;        // wave M extent (128 or 64)
  constexpr int M_REP = WTM / 16;      // 8 or 4
  constexpr int MH = M_REP / 2;        // 4 or 2
  constexpr int ABUFE = 256 * 64;      // elements per A buffer
  constexpr int BBUFE = BN * 64;
  constexpr int BBASE = 2 * ABUFE;
  constexpr int LOADS_A = 2;           // loads/thread per A half-tile (128 rows)
  constexpr int LOADS_B = BN / 128;    // loads/thread per B half-tile (BN/2 rows)
  constexpr int VM_STEADY = 2 * LOADS_B + LOADS_A;  // 6 or 4

  __shared__ __attribute__((aligned(16))) unsigned short lds[BBASE + 2 * BBUFE];

  // bijective XCD-chunked swizzle
  const int gx = gridDim.x, gy = gridDim.y;
  const int lid = blockIdx.x + gx * (blockIdx.y + gy * blockIdx.z);
  const int nwg = gx * gy * gridDim.z;
  const int q = nwg >> 3, r = nwg & 7;
  const int xcd = lid & 7, idx = lid >> 3;
  const int nl = (xcd < r ? xcd * (q + 1) : r * (q + 1) + (xcd - r) * q) + idx;
  const int bx = nl % gx, by = (nl / gx) % gy, bz = nl / (gx * gy);

  const int tid = threadIdx.x, wave = tid >> 6, lane = tid & 63;
  const int wr = wave / WN, wc = wave % WN;
  const int fr = lane & 15, fq = lane >> 4, sw = fr & 7;

  A  += (size_t)bz * sA;
  Bt += (size_t)bz * sB;
  const int m0 = by * 256;
  const int n0 = bx * BN;
  const int NT = K >> 6;

  f32x4 acc[M_REP][4] = {};
  bf16x8 a[MH][2], b[4][2];

  // ---- staging (linear LDS dest; XOR-swizzle realized via permuted source)
  auto stageA = [&](int t, int half) {
#pragma unroll
    for (int c = 0; c < LOADS_A; ++c) {
      const int s = c * THREADS + tid;          // 16B chunk index in half-tile
      const int rr = s >> 3;                    // row within half (0..127)
      const int col = ((tid & 7) ^ (rr & 7)) * 8;
      gload_lds16(A + (size_t)(m0 + half * 128 + rr) * lda + t * 64 + col,
                  &lds[(t & 1) * ABUFE + half * (128 * 64) + s * 8]);
    }
  };
  auto stageB = [&](int t, int half) {
#pragma unroll
    for (int c = 0; c < LOADS_B; ++c) {
      const int s = c * THREADS + tid;
      const int rr = s >> 3;
      const int col = ((tid & 7) ^ (rr & 7)) * 8;
      gload_lds16(Bt + (size_t)(n0 + half * (BN / 2) + rr) * ldb + t * 64 + col,
                  &lds[BBASE + (t & 1) * BBUFE + half * ((BN / 2) * 64) + s * 8]);
    }
  };
  // ---- fragment reads (swizzled)
  auto readA = [&](int buf, int mq) {
    const unsigned short* p = &lds[buf * ABUFE];
#pragma unroll
    for (int mm = 0; mm < MH; ++mm)
#pragma unroll
      for (int kk = 0; kk < 2; ++kk)
        a[mm][kk] = *(const bf16x8*)(p + (wr * WTM + mq * (WTM / 2) + mm * 16 + fr) * 64
                                       + ((kk * 4 + fq) ^ sw) * 8);
  };
  auto readB = [&](int buf, int nh) {
    const unsigned short* p = &lds[BBASE + buf * BBUFE];
#pragma unroll
    for (int nn = 0; nn < 2; ++nn)
#pragma unroll
      for (int kk = 0; kk < 2; ++kk)
        b[nh * 2 + nn][kk] = *(const bf16x8*)(p + (wc * 64 + (nh * 2 + nn) * 16 + fr) * 64
                                                + ((kk * 4 + fq) ^ sw) * 8);
  };
  auto mfmaQ = [&](int mq, int nh) {
    __builtin_amdgcn_s_setprio(1);
#pragma unroll
    for (int kk = 0; kk < 2; ++kk)
#pragma unroll
      for (int mm = 0; mm < MH; ++mm)
#pragma unroll
        for (int nn = 0; nn < 2; ++nn)
          acc[mq * MH + mm][nh * 2 + nn] = __builtin_amdgcn_mfma_f32_16x16x32_bf16(
              a[mm][kk], b[nh * 2 + nn][kk], acc[mq * MH + mm][nh * 2 + nn], 0, 0, 0);
    __builtin_amdgcn_s_setprio(0);
  };

  // ---- prologue: tile0 fully, tile1 {B0,B1,A0}
  stageA(0, 0); stageA(0, 1); stageB(0, 0); stageB(0, 1);
  if (NT > 1) { stageB(1, 0); stageB(1, 1); stageA(1, 0); vm_wait<VM_STEADY>(); }
  else        { vm_wait<0>(); }
  BARRIER();

  // ---- main loop: 4 phases per K-tile
  for (int t = 0; t < NT; ++t) {
    const int buf = t & 1;
    // ph1
    readA(buf, 0); readB(buf, 0);
    BARRIER(); SCHED0();
    mfmaQ(0, 0);
    SCHED0();
    BARRIER();
    // ph2
    readB(buf, 1);
    if (t + 1 < NT) stageA(t + 1, 1);
    BARRIER(); SCHED0();
    mfmaQ(0, 1);
    SCHED0();
    BARRIER();
    // ph3
    readA(buf, 1);
    if (t + 2 < NT) stageB(t + 2, 0);
    BARRIER(); SCHED0();
    mfmaQ(1, 0);
    SCHED0();
    BARRIER();
    // ph4
    if (t + 2 < NT) { stageB(t + 2, 1); stageA(t + 2, 0); vm_wait<VM_STEADY>(); }
    else            { vm_wait<0>(); }
    BARRIER(); SCHED0();
    mfmaQ(1, 1);
    SCHED0();
    BARRIER();
  }

  // ---- epilogue (nn innermost: 4 stores covering one 128B row-chunk stay
  //      adjacent -> L2 write combining)
  float bvc[4];
  if (EPI == 1 || EPI == 5) {
#pragma unroll
    for (int nn = 0; nn < 4; ++nn) bvc[nn] = bias[n0 + wc * 64 + nn * 16 + fr];
  }
#pragma unroll
  for (int mm = 0; mm < M_REP; ++mm) {
    const int rbase = m0 + wr * WTM + mm * 16 + fq * 4;
#pragma unroll
    for (int j = 0; j < 4; ++j) {
      const int row = rbase + j;
      float bvr = 0.f, rsc = 1.f;
      if (EPI == 2) bvr = bias[row];
      if (EPI == 5) rsc = __builtin_amdgcn_rcpf(rs[(size_t)bz * 2048 + row]);
      float part = 0.f;
#pragma unroll
      for (int nn = 0; nn < 4; ++nn) {
        const int col = n0 + wc * 64 + nn * 16 + fr;
        float v = acc[mm][nn][j];
        if      (EPI == 1) v = v * alpha + bvc[nn];
        else if (EPI == 2) v = v * alpha + bvr;
        else if (EPI == 3) { v = __expf(v * alpha); part += v; }
        else if (EPI == 5) v = v * rsc + bvc[nn];
        else               v = v * alpha;
        const size_t off = (size_t)bz * sC + (size_t)row * ldc + col;
        if      (EPI == 6) atomicAdd((float*)Cout + off, v);
        else if (OUT_F32)  ((float*)Cout)[off] = v;
        else               ((unsigned short*)Cout)[off] = f2bf(v);
      }
      if (EPI == 3) {
        part += __shfl_xor(part, 1); part += __shfl_xor(part, 2);
        part += __shfl_xor(part, 4); part += __shfl_xor(part, 8);
        if (fr == 0) atomicAdd(rs + (size_t)bz * 2048 + row, part);
      }
    }
  }
}

// ---------------------------------------------------------------------------
// fp32 -> bf16 straight convert, 2048 elements per block (grid = count/2048)
// ---------------------------------------------------------------------------
__global__ __launch_bounds__(256)
void convert_kernel(const float* __restrict__ x, unsigned short* __restrict__ xb)
{
  const int idx = (blockIdx.x * 256 + threadIdx.x) * 8;
  const float4 a = *(const float4*)(x + idx);
  const float4 b = *(const float4*)(x + idx + 4);
  unsigned u0 = (unsigned)f2bf(a.x) | ((unsigned)f2bf(a.y) << 16);
  unsigned u1 = (unsigned)f2bf(a.z) | ((unsigned)f2bf(a.w) << 16);
  unsigned u2 = (unsigned)f2bf(b.x) | ((unsigned)f2bf(b.y) << 16);
  unsigned u3 = (unsigned)f2bf(b.z) | ((unsigned)f2bf(b.w) << 16);
  uint4 o; o.x = u0; o.y = u1; o.z = u2; o.w = u3;
  *(uint4*)(xb + idx) = o;
}

// W fp32 [1024][1024] (k-major) -> Wt bf16 [1024][1024] (n-major), 3 weights
__global__ __launch_bounds__(256)
void transpose_w_kernel(const float* __restrict__ Wa, const float* __restrict__ Wb,
                        const float* __restrict__ Wc,
                        unsigned short* __restrict__ Wt)
{
  __shared__ float t[64][65];
  const float* W = (blockIdx.z == 0) ? Wa : (blockIdx.z == 1) ? Wb : Wc;
  unsigned short* out = Wt + (size_t)blockIdx.z * 1024 * 1024;
  const int k0 = blockIdx.y * 64;
  const int n0 = blockIdx.x * 64;
  const int tx = threadIdx.x & 63, ty = threadIdx.x >> 6;
#pragma unroll
  for (int r = ty; r < 64; r += 4)
    t[r][tx] = W[(size_t)(k0 + r) * 1024 + n0 + tx];
  __syncthreads();
#pragma unroll
  for (int r = ty; r < 64; r += 4)
    out[(size_t)(n0 + r) * 1024 + k0 + tx] = f2bf(t[tx][r]);
}

__global__ __launch_bounds__(256)
void bias_concat_kernel(const float* __restrict__ b1, const float* __restrict__ b2,
                        float* __restrict__ bc)
{
  const int i = blockIdx.x * 256 + threadIdx.x;
  bc[i] = (i < 1024) ? b1[i] : b2[i - 1024];
}

// bf[e] = b4[e] + sum_j b3[j] * W4[j][e]   (W4t bf16 [e][j], wave per e)
__global__ __launch_bounds__(256)
void bias_fold_kernel(const unsigned short* __restrict__ W4t,
                      const float* __restrict__ b3,
                      const float* __restrict__ b4,
                      float* __restrict__ bf)
{
  const int e = blockIdx.x * 4 + (threadIdx.x >> 6);
  const int lane = threadIdx.x & 63;
  float acc = 0.f;
#pragma unroll 4
  for (int i = 0; i < 16; ++i) {
    const int j = i * 64 + lane;
    acc += bf2f(W4t[(size_t)e * 1024 + j]) * b3[j];
  }
#pragma unroll
  for (int o = 32; o; o >>= 1) acc += __shfl_xor(acc, o);
  if (lane == 0) bf[e] = acc + b4[e];
}

// ---------------------------------------------------------------------------
extern "C" void kernel_launch(void* const* d_in, const int* in_sizes, int n_in,
                              void* d_out, int out_size, void* d_ws, size_t ws_size,
                              hipStream_t stream)
{
  const float* x  = (const float*)d_in[0];
  const float* W1 = (const float*)d_in[1];
  const float* b1 = (const float*)d_in[2];
  const float* W2 = (const float*)d_in[3];
  const float* b2 = (const float*)d_in[4];
  const float* W3 = (const float*)d_in[5];
  const float* b3 = (const float*)d_in[6];
  const float* W4 = (const float*)d_in[7];
  const float* b4 = (const float*)d_in[8];

  char* ws = (char*)d_ws;
  const size_t MB = 1024 * 1024;
  unsigned short* xb   = (unsigned short*)(ws);            // 16MB (dead after V't-proj)
  unsigned short* Wt   = (unsigned short*)(ws + 16 * MB);  // 6MB: [W1t, W2t, W4t]
  unsigned short* QK   = (unsigned short*)(ws + 24 * MB);  // 32MB: [8192][2048]
  unsigned short* Vt   = (unsigned short*)(ws + 56 * MB);  // 16MB: [4][1024][2048] = (x@W34)^T
  unsigned short* S    = (unsigned short*)(ws + 72 * MB);  // 32MB: [4][2048][2048] exp values
  // aliases inside S region (all dead before scores writes S):
  unsigned short* W3b  = (unsigned short*)(ws + 72 * MB);  // 2MB straight-converted W3
  float*          W34f = (float*)(ws + 74 * MB);           // 4MB fp32 split-K partials
  unsigned short* W34t = (unsigned short*)(ws + 78 * MB);  // 2MB (W3@W4)^T bf16
  float*          bc   = (float*)(ws + 80 * MB);           // 8KB b1||b2
  // aliases inside xb region (written only after xb dead):
  float*          rsum = (float*)ws;                       // 32KB per-row exp sums
  float*          bfv  = (float*)(ws + 32 * 1024);         // 4KB b3@W4 + b4

  unsigned short* W4t = Wt + 2 * 1048576;

  convert_kernel<<<4096, 256, 0, stream>>>(x, xb);
  transpose_w_kernel<<<dim3(16, 16, 3), 256, 0, stream>>>(W1, W2, W4, Wt);
  convert_kernel<<<512, 256, 0, stream>>>(W3, W3b);
  bias_concat_kernel<<<8, 256, 0, stream>>>(b1, b2, bc);

  // W34t[e][k] = sum_j W4t[e][j] * W3[k][j]  -- split-K (4 slices of 256)
  hipMemsetAsync(W34f, 0, 1024 * 1024 * sizeof(float), stream);
  gemm256<128, 6, true><<<dim3(8, 4, 4), 512, 0, stream>>>(
      W4t, W3b, nullptr, nullptr, W34f, 256, 1024, 1024, 1024, 1.f,
      256, 256, 0);
  convert_kernel<<<512, 256, 0, stream>>>(W34f, W34t);

  // fused Q+K projection: QK = xb @ [W1t;W2t]^T + [b1;b2]   (256 blocks)
  gemm256<256, 1, false><<<dim3(8, 32, 1), 512, 0, stream>>>(
      xb, Wt, bc, nullptr, QK, 1024, 1024, 1024, 2048, 1.f, 0, 0, 0);

  // V't[z][e][t] = sum_k W34t[e][k] * xb[z][t][k]           (256 blocks)
  gemm256<128, 0, false><<<dim3(16, 4, 4), 512, 0, stream>>>(
      W34t, xb, nullptr, nullptr, Vt, 1024, 1024, 1024, 2048, 1.f,
      0, 2048L * 1024, 1024L * 2048);

  // xb dead from here; rsum/bfv live in its region
  hipMemsetAsync(rsum, 0, 4 * 2048 * sizeof(float), stream);
  bias_fold_kernel<<<256, 256, 0, stream>>>(W4t, b3, b4, bfv);

  // scores: S[z] = exp((Q[z] @ K[z]^T) / 32), rowsum -> rsum  (256 blocks)
  gemm256<256, 3, false><<<dim3(8, 8, 4), 512, 0, stream>>>(
      QK, QK + 1024, nullptr, rsum, S, 1024, 2048, 2048, 2048, 0.03125f,
      2048L * 2048, 2048L * 2048, 2048L * 2048);

  // out[z] = (S[z] @ V'[z]) * rcp(rsum[row]) + bfv[col]  (fp32, 256 blocks)
  gemm256<128, 5, true><<<dim3(8, 8, 4), 512, 0, stream>>>(
      S, Vt, bfv, rsum, d_out, 2048, 2048, 2048, 1024, 1.f,
      2048L * 2048, 1024L * 2048, 2048L * 1024);
}